// Round 3
// baseline (129.992 us; speedup 1.0000x reference)
//
#include <hip/hip_runtime.h>
#include <math.h>

#define BB 16
#define TT 2048
#define FF 512
#define POOL_BLOCKS ((BB * TT) / 4)   // 8192 blocks, 4 waves each, 1 wave per output row
#define MASK_BLOCKS ((BB * TT) / 256) // 128 blocks for the mask tail

typedef float v4f __attribute__((ext_vector_type(4)));

// Kernel 1: wt[b,t] = sigmoid(dot(x[b,t,:], w) + bias). One wave (64 lanes) per row.
__global__ __launch_bounds__(256) void wt_kernel(const float* __restrict__ x,
                                                 const float* __restrict__ w,
                                                 const float* __restrict__ bias,
                                                 float* __restrict__ wt) {
    int gid  = blockIdx.x * 256 + threadIdx.x;
    int row  = gid >> 6;    // [0, B*T)
    int lane = gid & 63;
    const float* xr = x + (size_t)row * FF + lane * 8;
    const float* wr = w + lane * 8;
    float4 a0 = *(const float4*)xr;
    float4 a1 = *(const float4*)(xr + 4);
    float4 w0 = *(const float4*)wr;
    float4 w1 = *(const float4*)(wr + 4);
    float s = a0.x * w0.x + a0.y * w0.y + a0.z * w0.z + a0.w * w0.w
            + a1.x * w1.x + a1.y * w1.y + a1.z * w1.z + a1.w * w1.w;
#pragma unroll
    for (int off = 32; off > 0; off >>= 1) s += __shfl_xor(s, off, 64);
    if (lane == 0) {
        float z = s + bias[0];
        wt[row] = 1.0f / (1.0f + expf(-z));
    }
}

// Kernel 2: one WAVE per batch. Valley detect + wave-scan compaction, no barriers.
__global__ __launch_bounds__(64) void seg_kernel(const float* __restrict__ wt,
                                                 int* __restrict__ starts,
                                                 int* __restrict__ ends,
                                                 int* __restrict__ counts) {
    int b    = blockIdx.x;
    int lane = threadIdx.x;              // 0..63, 32 consecutive positions each
    const float* wrow = wt + b * TT;
    float v[32];
    const float4* p = (const float4*)(wrow + lane * 32);
#pragma unroll
    for (int k = 0; k < 8; ++k) {
        float4 f = p[k];
        v[4*k] = f.x; v[4*k+1] = f.y; v[4*k+2] = f.z; v[4*k+3] = f.w;
    }
    float left  = __shfl_up(v[31], 1, 64);
    float right = __shfl_down(v[0], 1, 64);
    unsigned int flags = 0;
#pragma unroll
    for (int k = 0; k < 32; ++k) {
        int t = lane * 32 + k;
        float prev = (k == 0)  ? left  : v[k - 1];
        float next = (k == 31) ? right : v[k + 1];
        bool val = (t > 0) && (t < TT - 1) && (v[k] < prev) && (v[k] < next);
        if (val) flags |= (1u << k);
    }
    int cnt = __popc(flags);
    int inc = cnt;
#pragma unroll
    for (int off = 1; off < 64; off <<= 1) {
        int y = __shfl_up(inc, off, 64);
        if (lane >= off) inc += y;
    }
    int total = __shfl(inc, 63, 64);
    int r = inc - cnt;
    int* sb = starts + b * TT;
    int* eb = ends + b * TT;
    unsigned int f = flags;
    while (f) {
        int k = __ffs(f) - 1;
        f &= f - 1;
        int t = lane * 32 + k;
        sb[r + 1] = t;
        eb[r] = t + 2;
        ++r;
    }
    if (lane == 0) {
        sb[0] = 0;
        eb[total] = TT;
        counts[b] = total + 1;
    }
}

// Kernel 3: fused pool + mask. Pool loop unrolled x4 (8 loads in flight per iter),
// nontemporal output stores to keep x resident in L2/L3.
__global__ __launch_bounds__(256) void pool_mask_kernel(const float* __restrict__ x,
                                                        const float* __restrict__ wt,
                                                        const int* __restrict__ starts,
                                                        const int* __restrict__ ends,
                                                        const int* __restrict__ counts,
                                                        const int* __restrict__ seq_len,
                                                        float* __restrict__ out,
                                                        float* __restrict__ mask_out) {
    int blk = blockIdx.x;
    if (blk >= POOL_BLOCKS) {
        int idx = (blk - POOL_BLOCKS) * 256 + threadIdx.x;   // [0, B*T)
        int b = idx >> 11;
        int t = idx & (TT - 1);
        int maxc = 0;
#pragma unroll
        for (int i = 0; i < BB; ++i) maxc = max(maxc, counts[i]);
        int len_b = min(seq_len[b], TT);
        int len0  = min(seq_len[0], TT);
        int nl = (int)((float)len_b / (float)len0 * (float)maxc);
        mask_out[idx] = (t < nl) ? 1.0f : 0.0f;
        return;
    }
    int gid  = blk * 256 + threadIdx.x;
    int row  = gid >> 6;        // b*T + j
    int lane = gid & 63;
    int b = row >> 11;          // T = 2048
    int j = row & (TT - 1);
    v4f acc0 = (v4f)(0.f);
    v4f acc1 = (v4f)(0.f);
    if (j < counts[b]) {
        int s = starts[row], e = ends[row];
        const float* xb   = x + (size_t)b * TT * FF + lane * 8;
        const float* wrow = wt + b * TT;
        float den = 0.f;
        for (int t = s; t < e; t += 4) {
            int i1 = (t + 1 < e) ? t + 1 : t;
            int i2 = (t + 2 < e) ? t + 2 : t;
            int i3 = (t + 3 < e) ? t + 3 : t;
            float w0 = wrow[t];
            float w1 = (t + 1 < e) ? wrow[i1] : 0.f;
            float w2 = (t + 2 < e) ? wrow[i2] : 0.f;
            float w3 = (t + 3 < e) ? wrow[i3] : 0.f;
            const v4f* p0 = (const v4f*)(xb + (size_t)t  * FF);
            const v4f* p1 = (const v4f*)(xb + (size_t)i1 * FF);
            const v4f* p2 = (const v4f*)(xb + (size_t)i2 * FF);
            const v4f* p3 = (const v4f*)(xb + (size_t)i3 * FF);
            v4f v00 = p0[0], v01 = p0[1];
            v4f v10 = p1[0], v11 = p1[1];
            v4f v20 = p2[0], v21 = p2[1];
            v4f v30 = p3[0], v31 = p3[1];
            acc0 += w0 * v00; acc1 += w0 * v01;
            acc0 += w1 * v10; acc1 += w1 * v11;
            acc0 += w2 * v20; acc1 += w2 * v21;
            acc0 += w3 * v30; acc1 += w3 * v31;
            den += w0 + w1 + w2 + w3;
        }
        float inv = 1.0f / fmaxf(den, 1e-6f);
        acc0 *= inv; acc1 *= inv;
    }
    float* orow = out + (size_t)row * FF + lane * 8;
    __builtin_nontemporal_store(acc0, (v4f*)orow);
    __builtin_nontemporal_store(acc1, (v4f*)(orow + 4));
}

extern "C" void kernel_launch(void* const* d_in, const int* in_sizes, int n_in,
                              void* d_out, int out_size, void* d_ws, size_t ws_size,
                              hipStream_t stream) {
    const float* x       = (const float*)d_in[0];
    const float* w_aggr  = (const float*)d_in[1];
    const float* b_aggr  = (const float*)d_in[2];
    const int*   seq_len = (const int*)d_in[3];

    float* pooled = (float*)d_out;
    float* mask   = (float*)d_out + (size_t)BB * TT * FF;

    float* wt    = (float*)d_ws;
    int* starts  = (int*)((char*)d_ws + (size_t)BB * TT * 4);
    int* ends    = starts + BB * TT;
    int* counts  = ends + BB * TT;

    const int rows = BB * TT;                 // 32768
    wt_kernel<<<rows / 4, 256, 0, stream>>>(x, w_aggr, b_aggr, wt);
    seg_kernel<<<BB, 64, 0, stream>>>(wt, starts, ends, counts);
    pool_mask_kernel<<<POOL_BLOCKS + MASK_BLOCKS, 256, 0, stream>>>(
        x, wt, starts, ends, counts, seq_len, pooled, mask);
}